// Round 8
// baseline (112.145 us; speedup 1.0000x reference)
//
#include <hip/hip_runtime.h>

#define CINC 64
#define COUT 64
#define HH 32
#define WW 32
#define BB 16
#define NSPLIT 4
#define CPS 16            // cin per split

typedef __attribute__((ext_vector_type(8))) short short8;
typedef __attribute__((ext_vector_type(4))) float floatx4;

__device__ __forceinline__ unsigned short f2bf(float f) {
    union { float f; unsigned int u; } c; c.f = f;
    unsigned int r = (c.u + 0x7FFFu + ((c.u >> 16) & 1u)) >> 16;
    return (unsigned short)r;
}

// W3 layout (COALESCED, round-6 verified):
// [split(4)][ts(36)][half(2)][nt(2)][q(4)][l15(16)][e(8)] bf16.
// Per (split,ts,half,nt) fragment, lane (q,l15) reads shorts [lane*8..lane*8+7]
// -> one fully-contiguous 1 KB wave read.
// Logical element: ts=tap*4+s, oc=half*32+nt*16+l15, cin=split*16+s*4+q, g=e.
__global__ __launch_bounds__(256) void wt_kernel(const float* __restrict__ sw,
                                                 const float* __restrict__ sc,
                                                 short* __restrict__ W3) {
    int idx = blockIdx.x * blockDim.x + threadIdx.x;
    const int total = NSPLIT * 36 * 2 * 2 * 4 * 16 * 8;   // 294,912
    if (idx >= total) return;
    int e    = idx & 7;
    int l15  = (idx >> 3) & 15;
    int q    = (idx >> 7) & 3;
    int nt   = (idx >> 9) & 1;
    int half = (idx >> 10) & 1;
    int tsid = idx >> 11;            // 0..143 = split*36 + ts
    int ts   = tsid % 36;
    int split = tsid / 36;
    int s = ts & 3, tap = ts >> 2;
    int oc = half * 32 + nt * 16 + l15;
    int cin = split * CPS + s * 4 + q;
    int g = e;
    int kh = tap / 3, kw = tap % 3;
    float w = sw[(((oc * CINC + cin) * 8 + g) * 3 + kh) * 3 + kw] * sc[oc * CINC + cin];
    W3[idx] = (short)f2bf(w);
}

// Counted vmcnt wait tied to the regs about to be consumed (true data dep).
#define VM_WAIT(N, a, b) asm volatile("s_waitcnt vmcnt(" #N ")" : "+v"(a), "+v"(b))
// Issue one step's two B-fragment loads (nt=0 at p, nt=1 at p+1024 B).
#define B_ISSUE(a, b, p)                                            \
    asm volatile("global_load_dwordx4 %0, %2, off\n\t"              \
                 "global_load_dwordx4 %1, %2, off offset:1024"      \
                 : "=&v"(a), "=&v"(b) : "v"(p))

// Fused bases + implicit-GEMM conv with in-block cin-split reduction.
// Grid: 256 blocks (b, row-pair). Block: 1024 thr = 16 waves = 4 waves/SIMD.
// Wave = (split = w&3, rowl = (w>>2)&1, oc-half = w>>3); mt=2, nt=2, 36 k-steps.
// B: depth-4 pinned pipeline, counted vmcnt, NO consume-copies (wait -> MFMA
// reads pb[s] directly -> reissue into pb[s]; the reissued load returns >=200cy
// after the MFMA read its sources, so write-after-read is safe — AITER pattern).
// A: plain C ds_reads (R7 proved the pinned A-pipeline is a null; let the
// compiler schedule lgkmcnt).
// *** DIAGNOSTIC THIS ROUND: main loop runs TWICE (pass 2 recomputes the
// identical acc, output unchanged; pass-1 acc kept alive via empty asm to
// defeat DCE per rule 17). Purpose: lift conv above the 41-us fill cutoff so
// its PMC counters (VGPR/MfmaUtil/VALUBusy/conflicts) become visible for the
// first time since R3. Remove the repeat next round. ***
__global__ __launch_bounds__(1024, 4) void conv_kernel(const float* __restrict__ xin,
                                                       const short* __restrict__ W3,
                                                       float* __restrict__ out) {
    __shared__ __align__(16) char smem[139264];
    short* A = (short*)smem;   // [split][r(4)][x(34)][slot(16)][e(8)], slot = cl^(x&15)
    float* P = (float*)smem;   // [split][row(128) = rowl*64+ocl][stride 36][x(32)]

    const int mb = blockIdx.x;
    const int b = mb >> 4;
    const int h0 = (mb & 15) * 2;
    const int t = threadIdx.x;
    const int wave = t >> 6;
    const int lane = t & 63;
    const int l15 = lane & 15;
    const int q = lane >> 4;
    const int split = wave & 3;
    const int rowl = (wave >> 2) & 1;
    const int n0 = (wave >> 3) * 32;

    const short* bp0 = W3 + (size_t)split * 73728 + (size_t)(wave >> 3) * 1024
                       + lane * 8;

    // ---- pass-0 B prologue early, so it overlaps the staging VALU ----
    short8 pb0[4], pb1[4];
    {
        const short* bp = bp0;
#pragma unroll
        for (int g = 0; g < 4; ++g) {
            B_ISSUE(pb0[g], pb1[g], bp);
            bp += 2048;
        }
    }

    // ---- stage A: closed-form uniform cubic B-spline bases -> bf16 LDS ----
    for (int u = t; u < 4 * 34 * CINC; u += 1024) {
        int x34 = u % 34;
        int rc = u / 34;                 // 0..255
        int c6 = rc & 63;                // cin 0..63
        int r = rc >> 6;
        int sp = c6 >> 4;                // which split's tile
        int cl = c6 & 15;
        int y = h0 + r;
        float v = 0.0f;
        if (y >= 1 && y <= HH && x34 >= 1 && x34 <= WW)
            v = xin[((b * CINC + c6) * HH + (y - 1)) * WW + (x34 - 1)];
        float sv = fmaf(v, 2.5f, 5.5f);               // (v + 2.2) / 0.4
        float cf = floorf(sv);
        int c = (int)cf;
        float f = sv - cf;
        float f2 = f * f, f3 = f2 * f;
        float omf = 1.0f - f;
        float w0 = f3 * (1.0f / 6.0f);
        float w1 = (1.0f + 3.0f * f + 3.0f * f2 - 3.0f * f3) * (1.0f / 6.0f);
        float w2 = (4.0f - 6.0f * f2 + 3.0f * f3) * (1.0f / 6.0f);
        float w3 = (omf * omf * omf) * (1.0f / 6.0f);
        short o8[8];
#pragma unroll
        for (int j = 0; j < 8; ++j) {
            float bj = (j == c) ? w0 : (j == c - 1) ? w1 : (j == c - 2) ? w2
                       : (j == c - 3) ? w3 : 0.0f;
            o8[j] = (short)f2bf(bj);
        }
        *(int4*)&A[sp * 17408 + (r * 34 + x34) * 128 + ((cl ^ (x34 & 15)) * 8)] =
            *(const int4*)o8;
    }
    __syncthreads();

    const int abase = split * 17408;
    floatx4 acc[2][2];

#define DO_MFMAS(B0, B1)                                                        \
    _Pragma("unroll")                                                           \
    for (int mt = 0; mt < 2; ++mt) {                                            \
        const int xi = mt * 16 + l15 + kw;                                      \
        short8 aF = *(const short8*)&A[abase + ((rowl + kh) * 34 + xi) * 128 +  \
                                       (((s * 4 + q) ^ (xi & 15)) * 8)];        \
        acc[mt][0] = __builtin_amdgcn_mfma_f32_16x16x32_bf16(aF, B0, acc[mt][0], 0, 0, 0); \
        acc[mt][1] = __builtin_amdgcn_mfma_f32_16x16x32_bf16(aF, B1, acc[mt][1], 0, 0, 0); \
    }

#pragma unroll
    for (int rep = 0; rep < 2; ++rep) {
#pragma unroll
        for (int mt = 0; mt < 2; ++mt)
#pragma unroll
            for (int nt = 0; nt < 2; ++nt) acc[mt][nt] = (floatx4)0.f;

        const short* bp = bp0;
        if (rep == 1) {                   // pass 1 issues its own prologue
#pragma unroll
            for (int g = 0; g < 4; ++g) {
                B_ISSUE(pb0[g], pb1[g], bp);
                bp += 2048;
            }
        } else {
            bp = bp0 + 4 * 2048;          // pass 0's prologue already issued
        }

        // ---- 36 steps = 9 taps x 4 k-quarters; consume-then-reissue ----
#pragma unroll
        for (int ts = 0; ts < 36; ++ts) {
            const int tap = ts >> 2, s = ts & 3;
            const int kh = tap / 3, kw = tap % 3;
            if (ts < 32)      { VM_WAIT(6, pb0[s], pb1[s]); }
            else if (ts == 32){ VM_WAIT(6, pb0[0], pb1[0]); }
            else if (ts == 33){ VM_WAIT(4, pb0[1], pb1[1]); }
            else if (ts == 34){ VM_WAIT(2, pb0[2], pb1[2]); }
            else              { VM_WAIT(0, pb0[3], pb1[3]); }
            DO_MFMAS(pb0[s], pb1[s])
            if (ts < 32) {                // reissue AFTER the MFMAs read pb[s]
                B_ISSUE(pb0[s], pb1[s], bp);
                bp += 2048;
            }
        }

        if (rep == 0) {
            // keep pass-0 results live (anti-DCE, rule 17); re-zeroed above
#pragma unroll
            for (int mt = 0; mt < 2; ++mt)
#pragma unroll
                for (int nt = 0; nt < 2; ++nt)
                    asm volatile("" :: "v"(acc[mt][nt]));
        }
    }
#undef DO_MFMAS

    // ---- epilogue: cross-split reduce via LDS, then direct out write ----
    __syncthreads();   // all A reads done; safe to alias with P
#pragma unroll
    for (int mt = 0; mt < 2; ++mt) {
#pragma unroll
        for (int nt = 0; nt < 2; ++nt) {
            const int row = rowl * 64 + n0 + nt * 16 + l15;   // 0..127
            // stride 36 floats (144 B): 16B-aligned float4 slots, banks spread
            *(floatx4*)(P + split * 4608 + row * 36 + mt * 16 + q * 4) = acc[mt][nt];
        }
    }
    __syncthreads();
    {
        const int x4 = (t & 7) * 4;        // 0..28
        const int row = t >> 3;            // 0..127 = rowl*64 + ocl
        const int ocl = row & 63;
        const int hh = h0 + (row >> 6);
        const int po = row * 36 + x4;
        floatx4 v = *(const floatx4*)(P + po)
                  + *(const floatx4*)(P + 4608 + po)
                  + *(const floatx4*)(P + 2 * 4608 + po)
                  + *(const floatx4*)(P + 3 * 4608 + po);
        *(floatx4*)(out + (((size_t)b * COUT + ocl) * HH + hh) * WW + x4) = v;
    }
}

extern "C" void kernel_launch(void* const* d_in, const int* in_sizes, int n_in,
                              void* d_out, int out_size, void* d_ws, size_t ws_size,
                              hipStream_t stream) {
    const float* x  = (const float*)d_in[0];
    const float* sw = (const float*)d_in[1];
    const float* sc = (const float*)d_in[2];
    float* out = (float*)d_out;
    short* W3 = (short*)d_ws;                           // 294,912 bf16 = 576 KB

    wt_kernel<<<(294912 + 255) / 256, 256, 0, stream>>>(sw, sc, W3);
    conv_kernel<<<256, 1024, 0, stream>>>(x, W3, out);
}

// Round 9
// 80.463 us; speedup vs baseline: 1.3938x; 1.3938x over previous
//
#include <hip/hip_runtime.h>

#define CINC 64
#define COUT 64
#define HH 32
#define WW 32
#define BB 16
#define NSPLIT 4
#define CPS 16            // cin per split

typedef __attribute__((ext_vector_type(8))) short short8;
typedef __attribute__((ext_vector_type(4))) float floatx4;

__device__ __forceinline__ unsigned short f2bf(float f) {
    union { float f; unsigned int u; } c; c.f = f;
    unsigned int r = (c.u + 0x7FFFu + ((c.u >> 16) & 1u)) >> 16;
    return (unsigned short)r;
}

// W3 layout (COALESCED, round-6 verified):
// [split(4)][ts(36)][half(2)][nt(2)][q(4)][l15(16)][e(8)] bf16.
// Per (split,ts,half,nt) fragment, lane (q,l15) reads shorts [lane*8..lane*8+7]
// -> one fully-contiguous 1 KB wave read.
// Logical element: ts=tap*4+s, oc=half*32+nt*16+l15, cin=split*16+s*4+q, g=e.
__global__ __launch_bounds__(256) void wt_kernel(const float* __restrict__ sw,
                                                 const float* __restrict__ sc,
                                                 short* __restrict__ W3) {
    int idx = blockIdx.x * blockDim.x + threadIdx.x;
    const int total = NSPLIT * 36 * 2 * 2 * 4 * 16 * 8;   // 294,912
    if (idx >= total) return;
    int e    = idx & 7;
    int l15  = (idx >> 3) & 15;
    int q    = (idx >> 7) & 3;
    int nt   = (idx >> 9) & 1;
    int half = (idx >> 10) & 1;
    int tsid = idx >> 11;            // 0..143 = split*36 + ts
    int ts   = tsid % 36;
    int split = tsid / 36;
    int s = ts & 3, tap = ts >> 2;
    int oc = half * 32 + nt * 16 + l15;
    int cin = split * CPS + s * 4 + q;
    int g = e;
    int kh = tap / 3, kw = tap % 3;
    float w = sw[(((oc * CINC + cin) * 8 + g) * 3 + kh) * 3 + kw] * sc[oc * CINC + cin];
    W3[idx] = (short)f2bf(w);
}

// Counted vmcnt wait tied to the regs about to be consumed (true data dep).
#define VM_WAIT(N, a, b) asm volatile("s_waitcnt vmcnt(" #N ")" : "+v"(a), "+v"(b))
// Issue one step's two B-fragment loads (nt=0 at p, nt=1 at p+1024 B).
#define B_ISSUE(a, b, p)                                            \
    asm volatile("global_load_dwordx4 %0, %2, off\n\t"              \
                 "global_load_dwordx4 %1, %2, off offset:1024"      \
                 : "=&v"(a), "=&v"(b) : "v"(p))

// Fused bases + implicit-GEMM conv with in-block cin-split reduction.
// Grid: 256 blocks (b, row-pair). Block: 1024 thr = 16 waves = 4 waves/SIMD.
// Wave = (split = w&3, rowl = (w>>2)&1, oc-half = w>>3); mt=2, nt=2, 36 k-steps.
// B: depth-4 pinned pipeline, counted vmcnt, copy-free consume-then-reissue.
// R8 diagnostic: per-SIMD wave-step cost is IDENTICAL at 2 and 4 waves/SIMD
// (441 vs 458 cyc) with no pipe saturated (Mfma 13.5%, VALU 19%) -> waves
// CONVOY: identical barrier-aligned instruction streams stall simultaneously.
// Fix: one-time s_sleep phase stagger (0/64/128/192 cyc) keyed by wave>>2 —
// the bits that differ among a SIMD's co-resident waves (SIMD = wave&3).
// The k-step loop is a pure sum, so phase offsets are semantically free.
__global__ __launch_bounds__(1024, 4) void conv_kernel(const float* __restrict__ xin,
                                                       const short* __restrict__ W3,
                                                       float* __restrict__ out) {
    __shared__ __align__(16) char smem[139264];
    short* A = (short*)smem;   // [split][r(4)][x(34)][slot(16)][e(8)], slot = cl^(x&15)
    float* P = (float*)smem;   // [split][row(128) = rowl*64+ocl][stride 36][x(32)]

    const int mb = blockIdx.x;
    const int b = mb >> 4;
    const int h0 = (mb & 15) * 2;
    const int t = threadIdx.x;
    const int wave = t >> 6;
    const int lane = t & 63;
    const int l15 = lane & 15;
    const int q = lane >> 4;
    const int split = wave & 3;
    const int rowl = (wave >> 2) & 1;
    const int n0 = (wave >> 3) * 32;

    // ---- B pipeline prologue: issue steps 0..3 (overlaps staging VALU) ----
    const short* bp = W3 + (size_t)split * 73728 + (size_t)(wave >> 3) * 1024
                      + lane * 8;
    short8 pb0[4], pb1[4];
#pragma unroll
    for (int g = 0; g < 4; ++g) {
        B_ISSUE(pb0[g], pb1[g], bp);
        bp += 2048;
    }

    // ---- stage A: closed-form uniform cubic B-spline bases -> bf16 LDS ----
    for (int u = t; u < 4 * 34 * CINC; u += 1024) {
        int x34 = u % 34;
        int rc = u / 34;                 // 0..255
        int c6 = rc & 63;                // cin 0..63
        int r = rc >> 6;
        int sp = c6 >> 4;                // which split's tile
        int cl = c6 & 15;
        int y = h0 + r;
        float v = 0.0f;
        if (y >= 1 && y <= HH && x34 >= 1 && x34 <= WW)
            v = xin[((b * CINC + c6) * HH + (y - 1)) * WW + (x34 - 1)];
        float sv = fmaf(v, 2.5f, 5.5f);               // (v + 2.2) / 0.4
        float cf = floorf(sv);
        int c = (int)cf;
        float f = sv - cf;
        float f2 = f * f, f3 = f2 * f;
        float omf = 1.0f - f;
        float w0 = f3 * (1.0f / 6.0f);
        float w1 = (1.0f + 3.0f * f + 3.0f * f2 - 3.0f * f3) * (1.0f / 6.0f);
        float w2 = (4.0f - 6.0f * f2 + 3.0f * f3) * (1.0f / 6.0f);
        float w3 = (omf * omf * omf) * (1.0f / 6.0f);
        short o8[8];
#pragma unroll
        for (int j = 0; j < 8; ++j) {
            float bj = (j == c) ? w0 : (j == c - 1) ? w1 : (j == c - 2) ? w2
                       : (j == c - 3) ? w3 : 0.0f;
            o8[j] = (short)f2bf(bj);
        }
        *(int4*)&A[sp * 17408 + (r * 34 + x34) * 128 + ((cl ^ (x34 & 15)) * 8)] =
            *(const int4*)o8;
    }
    __syncthreads();

    // ---- convoy-breaker: one-time wave-uniform phase stagger ----
    // Co-resident waves on a SIMD differ in wave>>2; sleep 0/64/128/192 cyc so
    // their per-step stall points (lgkmcnt before MFMA, vmcnt) interleave.
    {
        const int ph = (wave >> 2) & 3;       // wave-uniform -> scalar branch
        if (ph == 1)      __builtin_amdgcn_s_sleep(1);
        else if (ph == 2) __builtin_amdgcn_s_sleep(2);
        else if (ph == 3) __builtin_amdgcn_s_sleep(3);
    }

    floatx4 acc[2][2];
#pragma unroll
    for (int mt = 0; mt < 2; ++mt)
#pragma unroll
        for (int nt = 0; nt < 2; ++nt) acc[mt][nt] = (floatx4)0.f;

    const int abase = split * 17408;

#define DO_MFMAS(B0, B1)                                                        \
    _Pragma("unroll")                                                           \
    for (int mt = 0; mt < 2; ++mt) {                                            \
        const int xi = mt * 16 + l15 + kw;                                      \
        short8 aF = *(const short8*)&A[abase + ((rowl + kh) * 34 + xi) * 128 +  \
                                       (((s * 4 + q) ^ (xi & 15)) * 8)];        \
        acc[mt][0] = __builtin_amdgcn_mfma_f32_16x16x32_bf16(aF, B0, acc[mt][0], 0, 0, 0); \
        acc[mt][1] = __builtin_amdgcn_mfma_f32_16x16x32_bf16(aF, B1, acc[mt][1], 0, 0, 0); \
    }

    // ---- main loop: 36 steps = 9 taps x 4 k-quarters; consume-then-reissue ----
#pragma unroll
    for (int ts = 0; ts < 36; ++ts) {
        const int tap = ts >> 2, s = ts & 3;
        const int kh = tap / 3, kw = tap % 3;
        if (ts < 32)      { VM_WAIT(6, pb0[s], pb1[s]); }
        else if (ts == 32){ VM_WAIT(6, pb0[0], pb1[0]); }
        else if (ts == 33){ VM_WAIT(4, pb0[1], pb1[1]); }
        else if (ts == 34){ VM_WAIT(2, pb0[2], pb1[2]); }
        else              { VM_WAIT(0, pb0[3], pb1[3]); }
        DO_MFMAS(pb0[s], pb1[s])
        if (ts < 32) {                    // reissue AFTER the MFMAs read pb[s]
            B_ISSUE(pb0[s], pb1[s], bp);
            bp += 2048;
        }
    }
#undef DO_MFMAS

    // ---- epilogue: cross-split reduce via LDS, then direct out write ----
    __syncthreads();   // all A reads done; safe to alias with P
#pragma unroll
    for (int mt = 0; mt < 2; ++mt) {
#pragma unroll
        for (int nt = 0; nt < 2; ++nt) {
            const int row = rowl * 64 + n0 + nt * 16 + l15;   // 0..127
            // stride 36 floats (144 B): 16B-aligned float4 slots, banks spread
            *(floatx4*)(P + split * 4608 + row * 36 + mt * 16 + q * 4) = acc[mt][nt];
        }
    }
    __syncthreads();
    {
        const int x4 = (t & 7) * 4;        // 0..28
        const int row = t >> 3;            // 0..127 = rowl*64 + ocl
        const int ocl = row & 63;
        const int hh = h0 + (row >> 6);
        const int po = row * 36 + x4;
        floatx4 v = *(const floatx4*)(P + po)
                  + *(const floatx4*)(P + 4608 + po)
                  + *(const floatx4*)(P + 2 * 4608 + po)
                  + *(const floatx4*)(P + 3 * 4608 + po);
        *(floatx4*)(out + (((size_t)b * COUT + ocl) * HH + hh) * WW + x4) = v;
    }
}

extern "C" void kernel_launch(void* const* d_in, const int* in_sizes, int n_in,
                              void* d_out, int out_size, void* d_ws, size_t ws_size,
                              hipStream_t stream) {
    const float* x  = (const float*)d_in[0];
    const float* sw = (const float*)d_in[1];
    const float* sc = (const float*)d_in[2];
    float* out = (float*)d_out;
    short* W3 = (short*)d_ws;                           // 294,912 bf16 = 576 KB

    wt_kernel<<<(294912 + 255) / 256, 256, 0, stream>>>(sw, sc, W3);
    conv_kernel<<<256, 1024, 0, stream>>>(x, W3, out);
}

// Round 10
// 80.407 us; speedup vs baseline: 1.3947x; 1.0007x over previous
//
#include <hip/hip_runtime.h>

#define CINC 64
#define COUT 64
#define HH 32
#define WW 32
#define BB 16
#define NSPLIT 4
#define CPS 16            // cin per split

typedef __attribute__((ext_vector_type(8))) short short8;
typedef __attribute__((ext_vector_type(4))) float floatx4;

__device__ __forceinline__ unsigned short f2bf(float f) {
    union { float f; unsigned int u; } c; c.f = f;
    unsigned int r = (c.u + 0x7FFFu + ((c.u >> 16) & 1u)) >> 16;
    return (unsigned short)r;
}

// W3 layout (COALESCED, round-6 verified):
// [split(4)][ts(36)][half(2)][nt(2)][q(4)][l15(16)][e(8)] bf16.
// Per (split,ts,half,nt) fragment, lane (q,l15) reads shorts [lane*8..lane*8+7]
// -> one fully-contiguous 1 KB wave read. ts = tap*4 + s.
__global__ __launch_bounds__(256) void wt_kernel(const float* __restrict__ sw,
                                                 const float* __restrict__ sc,
                                                 short* __restrict__ W3) {
    int idx = blockIdx.x * blockDim.x + threadIdx.x;
    const int total = NSPLIT * 36 * 2 * 2 * 4 * 16 * 8;   // 294,912
    if (idx >= total) return;
    int e    = idx & 7;
    int l15  = (idx >> 3) & 15;
    int q    = (idx >> 7) & 3;
    int nt   = (idx >> 9) & 1;
    int half = (idx >> 10) & 1;
    int tsid = idx >> 11;            // 0..143 = split*36 + ts
    int ts   = tsid % 36;
    int split = tsid / 36;
    int s = ts & 3, tap = ts >> 2;
    int oc = half * 32 + nt * 16 + l15;
    int cin = split * CPS + s * 4 + q;
    int g = e;
    int kh = tap / 3, kw = tap % 3;
    float w = sw[(((oc * CINC + cin) * 8 + g) * 3 + kh) * 3 + kw] * sc[oc * CINC + cin];
    W3[idx] = (short)f2bf(w);
}

// Counted vmcnt wait tied to the regs about to be consumed (true data dep).
#define VM_WAIT(N, a, b) asm volatile("s_waitcnt vmcnt(" #N ")" : "+v"(a), "+v"(b))
// Issue one step's two B-fragment loads (nt=0 at p, nt=1 at p+1024 B).
#define B_ISSUE(a, b, p)                                            \
    asm volatile("global_load_dwordx4 %0, %2, off\n\t"              \
                 "global_load_dwordx4 %1, %2, off offset:1024"      \
                 : "=&v"(a), "=&v"(b) : "v"(p))

// Fused bases + implicit-GEMM conv with in-block cin-split reduction.
// Grid: 256 blocks (b, row-pair). Block: 1024 thr = 16 waves = 4 waves/SIMD.
// B: depth-4 pinned pipeline, counted vmcnt, copy-free consume-then-reissue.
//
// INTER-CU DESPREAD (this round): every block reads the entire 576 KB W3; with
// identical traversal order, all 32 blocks of an XCD convoy through the same
// 2 KB fragment simultaneously -> L2 line/bank pileup + duplicated HBM misses
// (R8: FETCH 45.9 MB vs ~13 MB footprint). Survives all intra-CU fixes (4
// nulls, R5/R7/R8/R9). Fix: rotate each block's traversal phase keyed on
// r = bid>>3 (same-XCD blocks share bid%8, so low bits can't work):
//   split' = (wave + r) & 3          (144 KB phase, 4 values)
//   half'  = ((wave>>3) + (r>>2))&1  (72 KB phase, 2 values)
//   s-start= (r>>3) & 3              (2 KB phase within tap, 4 values)
// -> 32 distinct phases = 32 blocks/XCD. The k-loop is a pure sum, so any
// traversal order is exact; role rotation is bijective per block (the 4 waves
// sharing a split' cover all (rowl,half) combos), so staging/epilogue unchanged.
__global__ __launch_bounds__(1024, 4) void conv_kernel(const float* __restrict__ xin,
                                                       const short* __restrict__ W3,
                                                       float* __restrict__ out) {
    __shared__ __align__(16) char smem[139264];
    short* A = (short*)smem;   // [split][r(4)][x(34)][slot(16)][e(8)], slot = cl^(x&15)
    float* P = (float*)smem;   // [split][row(128) = rowl*64+ocl][stride 36][x(32)]

    const int mb = blockIdx.x;
    const int b = mb >> 4;
    const int h0 = (mb & 15) * 2;
    const int t = threadIdx.x;
    const int wave = t >> 6;
    const int lane = t & 63;
    const int l15 = lane & 15;
    const int q = lane >> 4;

    const int r = mb >> 3;                       // varies within an XCD
    const int split = (wave + r) & 3;            // rotated split role
    const int rowl = (wave >> 2) & 1;
    const int hw = ((wave >> 3) + (r >> 2)) & 1; // rotated oc-half
    const int n0 = hw * 32;
    const int srot = (r >> 3) & 3;               // rotated s-quarter start

    // ---- B pipeline prologue: issue steps 0..3 (overlaps staging VALU) ----
    // Step ts consumes W3 fragment (tap = ts>>2, s = ((ts&3)+srot)&3).
    const short* bbase = W3 + (size_t)split * 73728 + (size_t)hw * 1024 + lane * 8;
    short8 pb0[4], pb1[4];
#pragma unroll
    for (int g = 0; g < 4; ++g) {
        const int sg = (g + srot) & 3;
        B_ISSUE(pb0[g], pb1[g], bbase + sg * 2048);
    }

    // ---- stage A: closed-form uniform cubic B-spline bases -> bf16 LDS ----
    for (int u = t; u < 4 * 34 * CINC; u += 1024) {
        int x34 = u % 34;
        int rc = u / 34;                 // 0..255
        int c6 = rc & 63;                // cin 0..63
        int rr = rc >> 6;
        int sp = c6 >> 4;                // which split's tile
        int cl = c6 & 15;
        int y = h0 + rr;
        float v = 0.0f;
        if (y >= 1 && y <= HH && x34 >= 1 && x34 <= WW)
            v = xin[((b * CINC + c6) * HH + (y - 1)) * WW + (x34 - 1)];
        float sv = fmaf(v, 2.5f, 5.5f);               // (v + 2.2) / 0.4
        float cf = floorf(sv);
        int c = (int)cf;
        float f = sv - cf;
        float f2 = f * f, f3 = f2 * f;
        float omf = 1.0f - f;
        float w0 = f3 * (1.0f / 6.0f);
        float w1 = (1.0f + 3.0f * f + 3.0f * f2 - 3.0f * f3) * (1.0f / 6.0f);
        float w2 = (4.0f - 6.0f * f2 + 3.0f * f3) * (1.0f / 6.0f);
        float w3 = (omf * omf * omf) * (1.0f / 6.0f);
        short o8[8];
#pragma unroll
        for (int j = 0; j < 8; ++j) {
            float bj = (j == c) ? w0 : (j == c - 1) ? w1 : (j == c - 2) ? w2
                       : (j == c - 3) ? w3 : 0.0f;
            o8[j] = (short)f2bf(bj);
        }
        *(int4*)&A[sp * 17408 + (rr * 34 + x34) * 128 + ((cl ^ (x34 & 15)) * 8)] =
            *(const int4*)o8;
    }
    __syncthreads();

    floatx4 acc[2][2];
#pragma unroll
    for (int mt = 0; mt < 2; ++mt)
#pragma unroll
        for (int nt = 0; nt < 2; ++nt) acc[mt][nt] = (floatx4)0.f;

    const int abase = split * 17408;

#define DO_MFMAS(B0, B1)                                                        \
    _Pragma("unroll")                                                           \
    for (int mt = 0; mt < 2; ++mt) {                                            \
        const int xi = mt * 16 + l15 + kw;                                      \
        short8 aF = *(const short8*)&A[abase + ((rowl + kh) * 34 + xi) * 128 +  \
                                       (((s * 4 + q) ^ (xi & 15)) * 8)];        \
        acc[mt][0] = __builtin_amdgcn_mfma_f32_16x16x32_bf16(aF, B0, acc[mt][0], 0, 0, 0); \
        acc[mt][1] = __builtin_amdgcn_mfma_f32_16x16x32_bf16(aF, B1, acc[mt][1], 0, 0, 0); \
    }

    // ---- main loop: 36 steps = 9 taps x 4 k-quarters (s rotated by srot) ----
    // Slot index = ts&3 (issue order); consumed fragment s = ((ts&3)+srot)&3.
    // Reissue for step ts+4: same s, tap+1 -> addr = bbase + ((tap+1)*4+s)*2048.
#pragma unroll
    for (int ts = 0; ts < 36; ++ts) {
        const int tap = ts >> 2, i4 = ts & 3;
        const int kh = tap / 3, kw = tap % 3;
        const int s = (i4 + srot) & 3;            // wave-uniform runtime
        if (ts < 32)      { VM_WAIT(6, pb0[i4], pb1[i4]); }
        else if (ts == 32){ VM_WAIT(6, pb0[0], pb1[0]); }
        else if (ts == 33){ VM_WAIT(4, pb0[1], pb1[1]); }
        else if (ts == 34){ VM_WAIT(2, pb0[2], pb1[2]); }
        else              { VM_WAIT(0, pb0[3], pb1[3]); }
        DO_MFMAS(pb0[i4], pb1[i4])
        if (ts < 32) {                    // reissue AFTER the MFMAs read pb[i4]
            B_ISSUE(pb0[i4], pb1[i4], bbase + ((tap + 1) * 4 + s) * 2048);
        }
    }
#undef DO_MFMAS

    // ---- epilogue: cross-split reduce via LDS, then direct out write ----
    __syncthreads();   // all A reads done; safe to alias with P
#pragma unroll
    for (int mt = 0; mt < 2; ++mt) {
#pragma unroll
        for (int nt = 0; nt < 2; ++nt) {
            const int row = rowl * 64 + n0 + nt * 16 + l15;   // 0..127
            // stride 36 floats (144 B): 16B-aligned float4 slots, banks spread
            *(floatx4*)(P + split * 4608 + row * 36 + mt * 16 + q * 4) = acc[mt][nt];
        }
    }
    __syncthreads();
    {
        const int x4 = (t & 7) * 4;        // 0..28
        const int row = t >> 3;            // 0..127 = rowl*64 + ocl
        const int ocl = row & 63;
        const int hh = h0 + (row >> 6);
        const int po = row * 36 + x4;
        floatx4 v = *(const floatx4*)(P + po)
                  + *(const floatx4*)(P + 4608 + po)
                  + *(const floatx4*)(P + 2 * 4608 + po)
                  + *(const floatx4*)(P + 3 * 4608 + po);
        *(floatx4*)(out + (((size_t)b * COUT + ocl) * HH + hh) * WW + x4) = v;
    }
}

extern "C" void kernel_launch(void* const* d_in, const int* in_sizes, int n_in,
                              void* d_out, int out_size, void* d_ws, size_t ws_size,
                              hipStream_t stream) {
    const float* x  = (const float*)d_in[0];
    const float* sw = (const float*)d_in[1];
    const float* sc = (const float*)d_in[2];
    float* out = (float*)d_out;
    short* W3 = (short*)d_ws;                           // 294,912 bf16 = 576 KB

    wt_kernel<<<(294912 + 255) / 256, 256, 0, stream>>>(sw, sc, W3);
    conv_kernel<<<256, 1024, 0, stream>>>(x, W3, out);
}